// Round 1
// baseline (94.301 us; speedup 1.0000x reference)
//
#include <hip/hip_runtime.h>

// Embedding forward = row gather: out[i, :] = weight[idx[i], :]
// N_IDX = 500k rows, D_EMB = 128 f32 = 512 B/row = 32 float4.
// Mapping: 32 threads per row, one float4 each -> fully coalesced
// 512 B contiguous read + write per row.

__global__ void __launch_bounds__(256)
embed_gather_kernel(const int* __restrict__ idx,
                    const float4* __restrict__ weight,  // [N_EMB * 32]
                    float4* __restrict__ out,           // [N_IDX * 32]
                    int n_idx) {
    int tid = blockIdx.x * blockDim.x + threadIdx.x;
    int row = tid >> 5;        // which output row
    int c   = tid & 31;        // which float4 within the row
    if (row < n_idx) {
        int r = idx[row];      // broadcast within the 32-thread group (L1 hit)
        out[(size_t)row * 32 + c] = weight[(size_t)r * 32 + c];
    }
}

extern "C" void kernel_launch(void* const* d_in, const int* in_sizes, int n_in,
                              void* d_out, int out_size, void* d_ws, size_t ws_size,
                              hipStream_t stream) {
    const int*    idx    = (const int*)d_in[0];     // input indices [N_IDX]
    const float4* weight = (const float4*)d_in[1];  // [N_EMB, 128] f32
    float4*       out    = (float4*)d_out;          // [N_IDX, 128] f32

    int n_idx = in_sizes[0];
    int total_threads = n_idx * 32;
    int block = 256;
    int grid = (total_threads + block - 1) / block;

    embed_gather_kernel<<<grid, block, 0, stream>>>(idx, weight, out, n_idx);
}

// Round 3
// 93.547 us; speedup vs baseline: 1.0081x; 1.0081x over previous
//
#include <hip/hip_runtime.h>

// Embedding forward = row gather: out[i, :] = weight[idx[i], :]
// N_IDX = 500k rows, D_EMB = 128 f32 = 512 B/row = 32 float4.
// Mapping: 32 threads per row, one 16B vector each -> fully coalesced.
// R3: same as R2 (nt store for zero-reuse output; cached weight reads)
// but using a native clang ext_vector_type, since __builtin_nontemporal_*
// rejects HIP_vector_type<float,4>.

typedef float f32x4 __attribute__((ext_vector_type(4)));

__global__ void __launch_bounds__(256)
embed_gather_kernel(const int* __restrict__ idx,
                    const f32x4* __restrict__ weight,  // [N_EMB * 32]
                    f32x4* __restrict__ out,           // [N_IDX * 32]
                    int n_idx) {
    int tid = blockIdx.x * blockDim.x + threadIdx.x;
    int row = tid >> 5;        // which output row
    int c   = tid & 31;        // which 16B chunk within the row
    if (row < n_idx) {
        int r = __builtin_nontemporal_load(&idx[row]);   // read-once stream
        f32x4 v = weight[(size_t)r * 32 + c];            // cached: reuse across repeats
        __builtin_nontemporal_store(v, &out[(size_t)row * 32 + c]);  // zero-reuse stream
    }
}

extern "C" void kernel_launch(void* const* d_in, const int* in_sizes, int n_in,
                              void* d_out, int out_size, void* d_ws, size_t ws_size,
                              hipStream_t stream) {
    const int*   idx    = (const int*)d_in[0];      // input indices [N_IDX]
    const f32x4* weight = (const f32x4*)d_in[1];    // [N_EMB, 128] f32
    f32x4*       out    = (f32x4*)d_out;            // [N_IDX, 128] f32

    int n_idx = in_sizes[0];
    int total_threads = n_idx * 32;
    int block = 256;
    int grid = (total_threads + block - 1) / block;

    embed_gather_kernel<<<grid, block, 0, stream>>>(idx, weight, out, n_idx);
}